// Round 6
// baseline (303.510 us; speedup 1.0000x reference)
//
#include <hip/hip_runtime.h>
#include <math.h>

#define N_V 12288
#define D_F 32
#define N_E 196608
#define KNN 6
#define EPSF 1e-12f

#define SEGS 16
#define JSEG (N_V / SEGS)          // 768 candidate columns per segment
#define SUBTILES (JSEG / 16)       // 48 j-subtiles per segment
#define BLOCK_T 512                // 8 waves
#define ROWS_PER_BLOCK 256         // 8 waves x 32 query rows
#define ROW_BLOCKS (N_V / ROWS_PER_BLOCK)  // 48 -> grid 48 x 16 = 768 blocks
#define NKEEP 5                    // top-5 non-self keys kept per (row, seg)
#define NEGF -3.0e38f

#define A_BYTES (JSEG * 64)        // 49152: A tiles, fragment-linear
#define M_OFF A_BYTES              // msq region at 49152
#define LDS_BYTES (A_BYTES + JSEG * 4)  // 52224

typedef __bf16 bf16x8 __attribute__((ext_vector_type(8)));
typedef float f32x4 __attribute__((ext_vector_type(4)));

static_assert(N_V % ROWS_PER_BLOCK == 0, "");
static_assert(SUBTILES % 8 == 0, "");
static_assert(JSEG % ROWS_PER_BLOCK == 0, "");

__device__ __forceinline__ unsigned short f2bf(float f) {
    unsigned u = __builtin_bit_cast(unsigned, f);
    unsigned r = u + 0x7fffu + ((u >> 16) & 1u);   // RNE
    return (unsigned short)(r >> 16);
}

__device__ __forceinline__ float bfu2f(unsigned hw_lo16) {   // low 16 bits -> float
    return __builtin_bit_cast(float, hw_lo16 << 16);
}
__device__ __forceinline__ float bfhi2f(unsigned u) {        // high 16 bits -> float
    return __builtin_bit_cast(float, u & 0xffff0000u);
}

// pack 8 f32 -> bf16x8 (RNE)
__device__ __forceinline__ bf16x8 pack8(float4 a, float4 b) {
    uint4 w;
    w.x = (unsigned)f2bf(a.x) | ((unsigned)f2bf(a.y) << 16);
    w.y = (unsigned)f2bf(a.z) | ((unsigned)f2bf(a.w) << 16);
    w.z = (unsigned)f2bf(b.x) | ((unsigned)f2bf(b.y) << 16);
    w.w = (unsigned)f2bf(b.z) | ((unsigned)f2bf(b.w) << 16);
    return __builtin_bit_cast(bf16x8, w);
}

// descending sorted 5-list insert: 1 max + 4 med3 (med3 is full-rate, R4)
__device__ __forceinline__ void ins5(float s[NKEEP], float nv) {
    float y0 = fmaxf(s[0], nv);
    float y1 = __builtin_amdgcn_fmed3f(s[0], s[1], nv);
    float y2 = __builtin_amdgcn_fmed3f(s[1], s[2], nv);
    float y3 = __builtin_amdgcn_fmed3f(s[2], s[3], nv);
    float y4 = __builtin_amdgcn_fmed3f(s[3], s[4], nv);
    s[0] = y0; s[1] = y1; s[2] = y2; s[3] = y3; s[4] = y4;
}

// descending sorted 6-list insert (diag blocks: self + top-5; self dropped at write)
__device__ __forceinline__ void ins6(float s[KNN], float nv) {
    float y0 = fmaxf(s[0], nv);
    float y1 = __builtin_amdgcn_fmed3f(s[0], s[1], nv);
    float y2 = __builtin_amdgcn_fmed3f(s[1], s[2], nv);
    float y3 = __builtin_amdgcn_fmed3f(s[2], s[3], nv);
    float y4 = __builtin_amdgcn_fmed3f(s[3], s[4], nv);
    float y5 = __builtin_amdgcn_fmed3f(s[4], s[5], nv);
    s[0] = y0; s[1] = y1; s[2] = y2; s[3] = y3; s[4] = y4; s[5] = y5;
}

#define SEL4_5(L, c) { ins5(L, (c)[0]); ins5(L, (c)[1]); ins5(L, (c)[2]); ins5(L, (c)[3]); }
#define SEL4_6(L, c) { ins6(L, (c)[0]); ins6(L, (c)[1]); ins6(L, (c)[2]); ins6(L, (c)[3]); }

// ---------- kernel 1: fused prep + MFMA gram + top-k + last-done row merge ----------
// Stage own segment from x (f32->bf16) into LDS fragment-linear + msq in LDS.
// seg==0 blocks publish bf16 xb for edge_kernel. Main loop: c-rotation (selects
// consume subtile it while MFMAs compute it+1), order pinned per iteration with
// sched_group_barrier {DS_READ 2, MFMA 2, VALU 40/48} — deterministic issue
// interleave WITHOUT completion waits (R5's asm-pin mistake). Branch-free loop:
// diag blocks (row range inside segment) run ins6 and drop slot 0 (self = strict
// max) at writeout; clean blocks run pure ins5. After cand write, last block per
// row-block (atomic counter) merges the 16 segment lists -> v and vertex out.
__global__ __launch_bounds__(BLOCK_T, 6) void topk_mega(
    const float* __restrict__ x, unsigned short* __restrict__ xb,
    float* __restrict__ cand, float* __restrict__ v, float* __restrict__ out,
    int* __restrict__ counters) {
    __shared__ alignas(16) char lds[LDS_BYTES];
    __shared__ int lastFlag;
    const int t = threadIdx.x;
    const int wave = t >> 6;
    const int lane = t & 63;
    const int quad = lane >> 4;
    const int l16 = lane & 15;

    const int rowbase = blockIdx.x * ROWS_PER_BLOCK + wave * 32;
    const int seg = blockIdx.y;
    const int j0 = seg * JSEG;

    // ---- stage segment A-tiles into LDS (each wave: 6 subtiles), f32->bf16,
    //      and per-col msq = -0.5*||x_j||^2 ----
#pragma unroll
    for (int k = 0; k < SUBTILES / 8; ++k) {
        const int it = wave + 8 * k;
        const int j = j0 + it * 16 + l16;
        const float4* xp = (const float4*)(x + (size_t)j * D_F);
        const float4 pA = xp[quad * 2];
        const float4 pB = xp[quad * 2 + 1];
        float s = pA.x * pA.x + pA.y * pA.y + pA.z * pA.z + pA.w * pA.w
                + pB.x * pB.x + pB.y * pB.y + pB.z * pB.z + pB.w * pB.w;
        s += __shfl_xor(s, 16, 64);
        s += __shfl_xor(s, 32, 64);
        const bf16x8 pk = pack8(pA, pB);
        *((uint4*)(lds + it * 1024) + lane) = __builtin_bit_cast(uint4, pk);
        if (quad == 0)
            *(float*)(lds + M_OFF + (size_t)(it * 16 + l16) * 4) = -0.5f * s;
    }

    // ---- B fragments: query rows, converted in-register from x ----
    const float4* q0p = (const float4*)(x + (size_t)(rowbase + l16) * D_F);
    const float4* q1p = (const float4*)(x + (size_t)(rowbase + 16 + l16) * D_F);
    const bf16x8 bfrag0 = pack8(q0p[quad * 2], q0p[quad * 2 + 1]);
    const bf16x8 bfrag1 = pack8(q1p[quad * 2], q1p[quad * 2 + 1]);

    // seg==0 blocks publish the bf16 matrix for edge_kernel (covers all rows)
    if (seg == 0) {
        *(uint4*)(xb + (size_t)(rowbase + l16) * D_F + quad * 8) =
            __builtin_bit_cast(uint4, bfrag0);
        *(uint4*)(xb + (size_t)(rowbase + 16 + l16) * D_F + quad * 8) =
            __builtin_bit_cast(uint4, bfrag1);
    }

    __syncthreads();

    const char* aBase = lds + lane * 16;
    const char* mBase = lds + M_OFF + quad * 16;
#define LDA(i) (*reinterpret_cast<const bf16x8*>(aBase + (i) * 1024))
#define LDM(i) (*reinterpret_cast<const f32x4*>(mBase + (i) * 64))
#define MFMA(a, b, m) __builtin_amdgcn_mfma_f32_16x16x32_bf16((a), (b), (m), 0, 0, 0)

    // block rows fully inside this segment? (256 | 768 -> all-or-nothing)
    const bool diag = ((unsigned)(blockIdx.x * ROWS_PER_BLOCK - j0) < (unsigned)JSEG);

    if (!diag) {
        // ---- clean path: dual top-5 lists per rt (4 independent chains) ----
        float tA0[NKEEP], tB0[NKEEP], tA1[NKEEP], tB1[NKEEP];
#pragma unroll
        for (int k = 0; k < NKEEP; ++k) {
            tA0[k] = NEGF; tB0[k] = NEGF; tA1[k] = NEGF; tB1[k] = NEGF;
        }
        bf16x8 a_nx = LDA(0); f32x4 m_nx = LDM(0);
        f32x4 c0 = MFMA(a_nx, bfrag0, m_nx);
        f32x4 c1 = MFMA(a_nx, bfrag1, m_nx);
        a_nx = LDA(1); m_nx = LDM(1);
#pragma unroll
        for (int it = 0; it < SUBTILES - 1; ++it) {
            const f32x4 cn0 = MFMA(a_nx, bfrag0, m_nx);
            const f32x4 cn1 = MFMA(a_nx, bfrag1, m_nx);
            const int itn = (it + 2 < SUBTILES) ? it + 2 : SUBTILES - 1;
            a_nx = LDA(itn); m_nx = LDM(itn);
            if (it & 1) { SEL4_5(tB0, c0); SEL4_5(tB1, c1); }
            else        { SEL4_5(tA0, c0); SEL4_5(tA1, c1); }
            __builtin_amdgcn_sched_group_barrier(0x100, 2, 0);  // 2 DS_READ
            __builtin_amdgcn_sched_group_barrier(0x008, 2, 0);  // 2 MFMA
            __builtin_amdgcn_sched_group_barrier(0x002, 40, 0); // 40 VALU (selects)
            c0 = cn0; c1 = cn1;
        }
        SEL4_5(tB0, c0); SEL4_5(tB1, c1);   // subtile 47 (odd)
#pragma unroll
        for (int k = 0; k < NKEEP; ++k) { ins5(tA0, tB0[k]); ins5(tA1, tB1[k]); }
#pragma unroll
        for (int rnd = 0; rnd < 2; ++rnd) {
            const int mask = 16 << rnd;
            float b[NKEEP];
#pragma unroll
            for (int k = 0; k < NKEEP; ++k) b[k] = __shfl_xor(tA0[k], mask, 64);
#pragma unroll
            for (int k = 0; k < NKEEP; ++k) ins5(tA0, b[k]);
#pragma unroll
            for (int k = 0; k < NKEEP; ++k) b[k] = __shfl_xor(tA1[k], mask, 64);
#pragma unroll
            for (int k = 0; k < NKEEP; ++k) ins5(tA1, b[k]);
        }
        if (quad == 0) {
            float* dst0 = cand + ((size_t)(rowbase + l16) * SEGS + seg) * NKEEP;
#pragma unroll
            for (int k = 0; k < NKEEP; ++k) dst0[k] = tA0[k];
            float* dst1 = cand + ((size_t)(rowbase + 16 + l16) * SEGS + seg) * NKEEP;
#pragma unroll
            for (int k = 0; k < NKEEP; ++k) dst1[k] = tA1[k];
        }
    } else {
        // ---- diag path: dual top-6 lists; slot 0 == self (strict max), dropped ----
        float tA0[KNN], tB0[KNN], tA1[KNN], tB1[KNN];
#pragma unroll
        for (int k = 0; k < KNN; ++k) {
            tA0[k] = NEGF; tB0[k] = NEGF; tA1[k] = NEGF; tB1[k] = NEGF;
        }
        bf16x8 a_nx = LDA(0); f32x4 m_nx = LDM(0);
        f32x4 c0 = MFMA(a_nx, bfrag0, m_nx);
        f32x4 c1 = MFMA(a_nx, bfrag1, m_nx);
        a_nx = LDA(1); m_nx = LDM(1);
#pragma unroll
        for (int it = 0; it < SUBTILES - 1; ++it) {
            const f32x4 cn0 = MFMA(a_nx, bfrag0, m_nx);
            const f32x4 cn1 = MFMA(a_nx, bfrag1, m_nx);
            const int itn = (it + 2 < SUBTILES) ? it + 2 : SUBTILES - 1;
            a_nx = LDA(itn); m_nx = LDM(itn);
            if (it & 1) { SEL4_6(tB0, c0); SEL4_6(tB1, c1); }
            else        { SEL4_6(tA0, c0); SEL4_6(tA1, c1); }
            __builtin_amdgcn_sched_group_barrier(0x100, 2, 0);  // 2 DS_READ
            __builtin_amdgcn_sched_group_barrier(0x008, 2, 0);  // 2 MFMA
            __builtin_amdgcn_sched_group_barrier(0x002, 48, 0); // 48 VALU (selects)
            c0 = cn0; c1 = cn1;
        }
        SEL4_6(tB0, c0); SEL4_6(tB1, c1);   // subtile 47 (odd)
#pragma unroll
        for (int k = 0; k < KNN; ++k) { ins6(tA0, tB0[k]); ins6(tA1, tB1[k]); }
#pragma unroll
        for (int rnd = 0; rnd < 2; ++rnd) {
            const int mask = 16 << rnd;
            float b[KNN];
#pragma unroll
            for (int k = 0; k < KNN; ++k) b[k] = __shfl_xor(tA0[k], mask, 64);
#pragma unroll
            for (int k = 0; k < KNN; ++k) ins6(tA0, b[k]);
#pragma unroll
            for (int k = 0; k < KNN; ++k) b[k] = __shfl_xor(tA1[k], mask, 64);
#pragma unroll
            for (int k = 0; k < KNN; ++k) ins6(tA1, b[k]);
        }
        if (quad == 0) {
            float* dst0 = cand + ((size_t)(rowbase + l16) * SEGS + seg) * NKEEP;
#pragma unroll
            for (int k = 1; k < KNN; ++k) dst0[k - 1] = tA0[k];   // drop self
            float* dst1 = cand + ((size_t)(rowbase + 16 + l16) * SEGS + seg) * NKEEP;
#pragma unroll
            for (int k = 1; k < KNN; ++k) dst1[k - 1] = tA1[k];
        }
    }
#undef LDA
#undef LDM
#undef MFMA

    // ---- last-done merge: the 16th block per row-block merges 256 rows -> v ----
    __threadfence();
    __syncthreads();
    if (t == 0) {
        const int old = atomicAdd(counters + blockIdx.x, 1);
        lastFlag = (old == SEGS - 1) ? 1 : 0;
    }
    __syncthreads();
    if (lastFlag) {
        __threadfence();   // acquire: see all 16 blocks' cand writes
        const int row = blockIdx.x * ROWS_PER_BLOCK + (t >> 1);
        const int h = t & 1;
        const float4* c = (const float4*)(cand + (size_t)row * (SEGS * NKEEP));  // 20 f4
        float mk[NKEEP];
#pragma unroll
        for (int k = 0; k < NKEEP; ++k) mk[k] = NEGF;
#pragma unroll
        for (int s = 0; s < 10; ++s) {
            const float4 q = c[h * 10 + s];
            ins5(mk, q.x); ins5(mk, q.y); ins5(mk, q.z); ins5(mk, q.w);
        }
        {
            float b[NKEEP];
#pragma unroll
            for (int k = 0; k < NKEEP; ++k) b[k] = __shfl_xor(mk[k], 1, 64);
#pragma unroll
            for (int k = 0; k < NKEEP; ++k) ins5(mk, b[k]);
        }
        const float4* xp = (const float4*)(x + (size_t)row * D_F);
        float sq = 0.f;
#pragma unroll
        for (int d = 0; d < 4; ++d) {
            const float4 p = xp[h * 4 + d];
            sq += p.x * p.x + p.y * p.y + p.z * p.z + p.w * p.w;
        }
        sq += __shfl_xor(sq, 1, 64);
        if (h == 0) {
            const float msqi = -0.5f * sq;
            float ssum = 0.f;
#pragma unroll
            for (int m = 0; m < NKEEP; ++m) {
                const float d2 = -2.0f * (mk[m] + msqi);   // sq_i - 2*key
                ssum += expf(-sqrtf(fmaxf(d2, EPSF)));
            }
            const float vi = 1.0f - ssum / (float)KNN;
            v[row] = vi;
            out[2 * row] = vi;
            out[2 * row + 1] = 0.0f;
        }
    }
}

// ---------- kernel 2: edge filtration (bf16 gather: 1 line per row) ----------
__global__ __launch_bounds__(256) void edge_kernel(const unsigned short* __restrict__ xb,
                                                   const int* __restrict__ ei,
                                                   const float* __restrict__ v,
                                                   float* __restrict__ out) {
    int e = blockIdx.x * 256 + threadIdx.x;
    if (e >= N_E) return;
    const int u = ei[e];
    const int w = ei[N_E + e];
    const uint4* xu = (const uint4*)(xb + (size_t)u * D_F);
    const uint4* xw = (const uint4*)(xb + (size_t)w * D_F);
    float acc = 0.f;
#pragma unroll
    for (int d = 0; d < 4; ++d) {
        const uint4 p = xu[d];
        const uint4 q = xw[d];
#pragma unroll
        for (int c = 0; c < 4; ++c) {
            const unsigned pu = (&p.x)[c];
            const unsigned qu = (&q.x)[c];
            const float d0 = bfu2f(pu) - bfu2f(qu);
            const float d1 = bfhi2f(pu) - bfhi2f(qu);
            acc = fmaf(d0, d0, acc);
            acc = fmaf(d1, d1, acc);
        }
    }
    const float enorm = sqrtf(fmaxf(acc, EPSF));
    const float ey = 1.0f - expf(-enorm);
    const float ev = fmaxf(v[u], v[w]);
    out[2 * (N_V + e) + 0] = ev;
    out[2 * (N_V + e) + 1] = ey;
}

extern "C" void kernel_launch(void* const* d_in, const int* in_sizes, int n_in,
                              void* d_out, int out_size, void* d_ws, size_t ws_size,
                              hipStream_t stream) {
    const float* x = (const float*)d_in[0];
    const int* ei = (const int*)d_in[1];
    float* out = (float*)d_out;
    char* ws = (char*)d_ws;

    unsigned short* xb = (unsigned short*)ws;                       // 786432 B
    float* v    = (float*)(ws + 786432);                            // 49152 B
    float* cand = (float*)(ws + 786432 + 49152);                    // 3932160 B
    int* counters = (int*)(ws + 786432 + 49152 + 3932160);          // 192 B

    hipMemsetAsync(counters, 0, ROW_BLOCKS * sizeof(int), stream);

    dim3 g1(ROW_BLOCKS, SEGS);
    topk_mega<<<g1, BLOCK_T, 0, stream>>>(x, xb, cand, v, out, counters);

    edge_kernel<<<N_E / 256, 256, 0, stream>>>(xb, ei, v, out);
}

// Round 7
// 278.023 us; speedup vs baseline: 1.0917x; 1.0917x over previous
//
#include <hip/hip_runtime.h>
#include <math.h>

#define N_V 12288
#define D_F 32
#define N_E 196608
#define KNN 6
#define EPSF 1e-12f

#define SEGS 16
#define JSEG (N_V / SEGS)          // 768 candidate columns per segment
#define SUBTILES (JSEG / 16)       // 48 j-subtiles per segment
#define BLOCK_T 512                // 8 waves
#define ROWS_PER_BLOCK 256         // 8 waves x 32 query rows
#define ROW_BLOCKS (N_V / ROWS_PER_BLOCK)  // 48 -> grid 48 x 16 = 768 blocks (3/CU)
#define NKEEP 5                    // top-5 non-self keys kept per (row, seg)
#define NEGF -3.0e38f

#define A_BYTES (JSEG * 64)        // 49152: A tiles, fragment-linear
#define M_OFF A_BYTES              // msq region at 49152
#define LDS_BYTES (A_BYTES + JSEG * 4)  // 52224

typedef __bf16 bf16x8 __attribute__((ext_vector_type(8)));
typedef float f32x4 __attribute__((ext_vector_type(4)));

static_assert(N_V % ROWS_PER_BLOCK == 0, "");
static_assert(SUBTILES % 8 == 0, "");

__device__ __forceinline__ unsigned short f2bf(float f) {
    unsigned u = __builtin_bit_cast(unsigned, f);
    unsigned r = u + 0x7fffu + ((u >> 16) & 1u);   // RNE
    return (unsigned short)(r >> 16);
}

__device__ __forceinline__ float bfu2f(unsigned hw_lo16) {   // low 16 bits -> float
    return __builtin_bit_cast(float, hw_lo16 << 16);
}
__device__ __forceinline__ float bfhi2f(unsigned u) {        // high 16 bits -> float
    return __builtin_bit_cast(float, u & 0xffff0000u);
}

// pack 8 f32 -> bf16x8 (RNE)
__device__ __forceinline__ bf16x8 pack8(float4 a, float4 b) {
    uint4 w;
    w.x = (unsigned)f2bf(a.x) | ((unsigned)f2bf(a.y) << 16);
    w.y = (unsigned)f2bf(a.z) | ((unsigned)f2bf(a.w) << 16);
    w.z = (unsigned)f2bf(b.x) | ((unsigned)f2bf(b.y) << 16);
    w.w = (unsigned)f2bf(b.z) | ((unsigned)f2bf(b.w) << 16);
    return __builtin_bit_cast(bf16x8, w);
}

// descending sorted 5-list insert: 1 max + 4 med3 (med3 full-rate; R4 proved
// the 9-op min/max variant strictly worse)
__device__ __forceinline__ void ins5(float s[NKEEP], float nv) {
    float y0 = fmaxf(s[0], nv);
    float y1 = __builtin_amdgcn_fmed3f(s[0], s[1], nv);
    float y2 = __builtin_amdgcn_fmed3f(s[1], s[2], nv);
    float y3 = __builtin_amdgcn_fmed3f(s[2], s[3], nv);
    float y4 = __builtin_amdgcn_fmed3f(s[3], s[4], nv);
    s[0] = y0; s[1] = y1; s[2] = y2; s[3] = y3; s[4] = y4;
}

// ---------- kernel 1: fused prep + MFMA gram + top-5 + last-done row merge ----------
// Staging (R5, proven): block converts its 768-col segment f32->bf16 into LDS
// fragment-linear + msq in LDS; seg==0 blocks publish bf16 xb for edge_kernel.
// Main loop (R3, proven 42.7us): plain full unroll, ds_read_b128 base+imm,
// 2 MFMA, wave-uniform per-subtile self-poison, 8x ins5. NO scheduling
// directives (R4 minmax / R5 asm-pin / R6 SGB all regressed; SGB caused a
// 39 MB/dispatch scratch spill).
// Tail (R6, proven): last block per row-block (atomic counter) merges the 16
// segment lists -> v + vertex out rows.
__global__ __launch_bounds__(BLOCK_T, 6) void topk_mega(
    const float* __restrict__ x, unsigned short* __restrict__ xb,
    float* __restrict__ cand, float* __restrict__ v, float* __restrict__ out,
    int* __restrict__ counters) {
    __shared__ alignas(16) char lds[LDS_BYTES];
    __shared__ int lastFlag;
    const int t = threadIdx.x;
    const int wave = t >> 6;
    const int lane = t & 63;
    const int quad = lane >> 4;
    const int l16 = lane & 15;

    const int rowbase = blockIdx.x * ROWS_PER_BLOCK + wave * 32;
    const int seg = blockIdx.y;
    const int j0 = seg * JSEG;

    // ---- stage segment A-tiles into LDS (each wave: 6 subtiles), f32->bf16,
    //      and per-col msq = -0.5*||x_j||^2 ----
#pragma unroll
    for (int k = 0; k < SUBTILES / 8; ++k) {
        const int it = wave + 8 * k;
        const int j = j0 + it * 16 + l16;
        const float4* xp = (const float4*)(x + (size_t)j * D_F);
        const float4 pA = xp[quad * 2];
        const float4 pB = xp[quad * 2 + 1];
        float s = pA.x * pA.x + pA.y * pA.y + pA.z * pA.z + pA.w * pA.w
                + pB.x * pB.x + pB.y * pB.y + pB.z * pB.z + pB.w * pB.w;
        s += __shfl_xor(s, 16, 64);
        s += __shfl_xor(s, 32, 64);
        const bf16x8 pk = pack8(pA, pB);
        *((uint4*)(lds + it * 1024) + lane) = __builtin_bit_cast(uint4, pk);
        if (quad == 0)
            *(float*)(lds + M_OFF + (size_t)(it * 16 + l16) * 4) = -0.5f * s;
    }

    // ---- B fragments: query rows, converted in-register from x ----
    const float4* q0p = (const float4*)(x + (size_t)(rowbase + l16) * D_F);
    const float4* q1p = (const float4*)(x + (size_t)(rowbase + 16 + l16) * D_F);
    const bf16x8 bfrag0 = pack8(q0p[quad * 2], q0p[quad * 2 + 1]);
    const bf16x8 bfrag1 = pack8(q1p[quad * 2], q1p[quad * 2 + 1]);

    // seg==0 blocks publish the bf16 matrix for edge_kernel (covers all rows)
    if (seg == 0) {
        *(uint4*)(xb + (size_t)(rowbase + l16) * D_F + quad * 8) =
            __builtin_bit_cast(uint4, bfrag0);
        *(uint4*)(xb + (size_t)(rowbase + 16 + l16) * D_F + quad * 8) =
            __builtin_bit_cast(uint4, bfrag1);
    }

    __syncthreads();

    float tk0[NKEEP], tk1[NKEEP];
#pragma unroll
    for (int k = 0; k < NKEEP; ++k) { tk0[k] = NEGF; tk1[k] = NEGF; }

    // lane's self position inside a matching subtile: quad*4+reg == l16
    const int selfreg = (quad == (l16 >> 2)) ? (l16 & 3) : 8;
    const int rb0 = rowbase;
    const int rb1 = rowbase + 16;

    const char* aBase = lds + lane * 16;
    const char* mBase = lds + M_OFF + quad * 16;

#pragma unroll
    for (int it = 0; it < SUBTILES; ++it) {
        const bf16x8 a = *reinterpret_cast<const bf16x8*>(aBase + it * 1024);
        const f32x4 m = *reinterpret_cast<const f32x4*>(mBase + it * 64);

        f32x4 c0 = __builtin_amdgcn_mfma_f32_16x16x32_bf16(a, bfrag0, m, 0, 0, 0);
        f32x4 c1 = __builtin_amdgcn_mfma_f32_16x16x32_bf16(a, bfrag1, m, 0, 0, 0);

        const int jt = j0 + (it << 4);
        if (jt == rb0) {   // wave-uniform: this subtile contains rt=0 self diag
            c0[0] = (selfreg == 0) ? NEGF : c0[0];
            c0[1] = (selfreg == 1) ? NEGF : c0[1];
            c0[2] = (selfreg == 2) ? NEGF : c0[2];
            c0[3] = (selfreg == 3) ? NEGF : c0[3];
        }
        if (jt == rb1) {   // wave-uniform: this subtile contains rt=1 self diag
            c1[0] = (selfreg == 0) ? NEGF : c1[0];
            c1[1] = (selfreg == 1) ? NEGF : c1[1];
            c1[2] = (selfreg == 2) ? NEGF : c1[2];
            c1[3] = (selfreg == 3) ? NEGF : c1[3];
        }

        ins5(tk0, c0[0]); ins5(tk0, c0[1]); ins5(tk0, c0[2]); ins5(tk0, c0[3]);
        ins5(tk1, c1[0]); ins5(tk1, c1[1]); ins5(tk1, c1[2]); ins5(tk1, c1[3]);
    }

    // ---- cross-quad merge via shuffles (row's lists live in 4 quads, same l16) ----
#pragma unroll
    for (int rnd = 0; rnd < 2; ++rnd) {
        const int mask = 16 << rnd;
        float b[NKEEP];
#pragma unroll
        for (int k = 0; k < NKEEP; ++k) b[k] = __shfl_xor(tk0[k], mask, 64);
#pragma unroll
        for (int k = 0; k < NKEEP; ++k) ins5(tk0, b[k]);
#pragma unroll
        for (int k = 0; k < NKEEP; ++k) b[k] = __shfl_xor(tk1[k], mask, 64);
#pragma unroll
        for (int k = 0; k < NKEEP; ++k) ins5(tk1, b[k]);
    }

    if (quad == 0) {
        const int g0 = rowbase + l16;
        float* dst0 = cand + ((size_t)g0 * SEGS + seg) * NKEEP;
#pragma unroll
        for (int k = 0; k < NKEEP; ++k) dst0[k] = tk0[k];
        const int g1 = rowbase + 16 + l16;
        float* dst1 = cand + ((size_t)g1 * SEGS + seg) * NKEEP;
#pragma unroll
        for (int k = 0; k < NKEEP; ++k) dst1[k] = tk1[k];
    }

    // ---- last-done merge: the 16th block per row-block merges 256 rows -> v ----
    __threadfence();
    __syncthreads();
    if (t == 0) {
        const int old = atomicAdd(counters + blockIdx.x, 1);
        lastFlag = (old == SEGS - 1) ? 1 : 0;
    }
    __syncthreads();
    if (lastFlag) {
        __threadfence();   // acquire: see all 16 blocks' cand writes
        const int row = blockIdx.x * ROWS_PER_BLOCK + (t >> 1);
        const int h = t & 1;
        const float4* c = (const float4*)(cand + (size_t)row * (SEGS * NKEEP));  // 20 f4
        float mk[NKEEP];
#pragma unroll
        for (int k = 0; k < NKEEP; ++k) mk[k] = NEGF;
#pragma unroll
        for (int s = 0; s < 10; ++s) {
            const float4 q = c[h * 10 + s];
            ins5(mk, q.x); ins5(mk, q.y); ins5(mk, q.z); ins5(mk, q.w);
        }
        {
            float b[NKEEP];
#pragma unroll
            for (int k = 0; k < NKEEP; ++k) b[k] = __shfl_xor(mk[k], 1, 64);
#pragma unroll
            for (int k = 0; k < NKEEP; ++k) ins5(mk, b[k]);
        }
        const float4* xp = (const float4*)(x + (size_t)row * D_F);
        float sq = 0.f;
#pragma unroll
        for (int d = 0; d < 4; ++d) {
            const float4 p = xp[h * 4 + d];
            sq += p.x * p.x + p.y * p.y + p.z * p.z + p.w * p.w;
        }
        sq += __shfl_xor(sq, 1, 64);
        if (h == 0) {
            const float msqi = -0.5f * sq;
            float ssum = 0.f;
#pragma unroll
            for (int m = 0; m < NKEEP; ++m) {
                const float d2 = -2.0f * (mk[m] + msqi);   // sq_i - 2*key
                ssum += expf(-sqrtf(fmaxf(d2, EPSF)));
            }
            const float vi = 1.0f - ssum / (float)KNN;
            v[row] = vi;
            out[2 * row] = vi;
            out[2 * row + 1] = 0.0f;
        }
    }
}

// ---------- kernel 2: edge filtration (bf16 gather: 1 line per row) ----------
__global__ __launch_bounds__(256) void edge_kernel(const unsigned short* __restrict__ xb,
                                                   const int* __restrict__ ei,
                                                   const float* __restrict__ v,
                                                   float* __restrict__ out) {
    int e = blockIdx.x * 256 + threadIdx.x;
    if (e >= N_E) return;
    const int u = ei[e];
    const int w = ei[N_E + e];
    const uint4* xu = (const uint4*)(xb + (size_t)u * D_F);
    const uint4* xw = (const uint4*)(xb + (size_t)w * D_F);
    float acc = 0.f;
#pragma unroll
    for (int d = 0; d < 4; ++d) {
        const uint4 p = xu[d];
        const uint4 q = xw[d];
#pragma unroll
        for (int c = 0; c < 4; ++c) {
            const unsigned pu = (&p.x)[c];
            const unsigned qu = (&q.x)[c];
            const float d0 = bfu2f(pu) - bfu2f(qu);
            const float d1 = bfhi2f(pu) - bfhi2f(qu);
            acc = fmaf(d0, d0, acc);
            acc = fmaf(d1, d1, acc);
        }
    }
    const float enorm = sqrtf(fmaxf(acc, EPSF));
    const float ey = 1.0f - expf(-enorm);
    const float ev = fmaxf(v[u], v[w]);
    out[2 * (N_V + e) + 0] = ev;
    out[2 * (N_V + e) + 1] = ey;
}

extern "C" void kernel_launch(void* const* d_in, const int* in_sizes, int n_in,
                              void* d_out, int out_size, void* d_ws, size_t ws_size,
                              hipStream_t stream) {
    const float* x = (const float*)d_in[0];
    const int* ei = (const int*)d_in[1];
    float* out = (float*)d_out;
    char* ws = (char*)d_ws;

    unsigned short* xb = (unsigned short*)ws;                       // 786432 B
    float* v    = (float*)(ws + 786432);                            // 49152 B
    float* cand = (float*)(ws + 786432 + 49152);                    // 3932160 B
    int* counters = (int*)(ws + 786432 + 49152 + 3932160);          // 192 B

    hipMemsetAsync(counters, 0, ROW_BLOCKS * sizeof(int), stream);

    dim3 g1(ROW_BLOCKS, SEGS);
    topk_mega<<<g1, BLOCK_T, 0, stream>>>(x, xb, cand, v, out, counters);

    edge_kernel<<<N_E / 256, 256, 0, stream>>>(xb, ei, v, out);
}

// Round 8
// 101.354 us; speedup vs baseline: 2.9946x; 2.7431x over previous
//
#include <hip/hip_runtime.h>
#include <math.h>

#define N_V 12288
#define D_F 32
#define N_E 196608
#define KNN 6
#define EPSF 1e-12f

#define SEGS 16
#define JSEG (N_V / SEGS)          // 768 candidate columns per segment
#define SUBTILES (JSEG / 16)       // 48 j-subtiles per segment
#define BLOCK_T 256                // 4 waves
#define ROWS_PER_BLOCK 256         // 4 waves x 64 query rows (4 B-frags/wave)
#define ROW_BLOCKS (N_V / ROWS_PER_BLOCK)  // 48 -> grid 48 x 16 = 768 blocks (3/CU)
#define NKEEP 5                    // top-5 non-self keys kept per (row, seg)
#define NEGF -3.0e38f

#define A_BYTES (JSEG * 64)        // 49152: A tiles, fragment-linear
#define M_OFF A_BYTES              // msq region at 49152
#define LDS_BYTES (A_BYTES + JSEG * 4)  // 52224 (R3-proven config)

typedef __bf16 bf16x8 __attribute__((ext_vector_type(8)));
typedef float f32x4 __attribute__((ext_vector_type(4)));

static_assert(N_V % ROWS_PER_BLOCK == 0, "");
static_assert(SUBTILES % 4 == 0, "");

__device__ __forceinline__ unsigned short f2bf(float f) {
    unsigned u = __builtin_bit_cast(unsigned, f);
    unsigned r = u + 0x7fffu + ((u >> 16) & 1u);   // RNE
    return (unsigned short)(r >> 16);
}

__device__ __forceinline__ float bfu2f(unsigned hw_lo16) {   // low 16 bits -> float
    return __builtin_bit_cast(float, hw_lo16 << 16);
}
__device__ __forceinline__ float bfhi2f(unsigned u) {        // high 16 bits -> float
    return __builtin_bit_cast(float, u & 0xffff0000u);
}

// descending sorted 5-list insert: 1 max + 4 med3 (med3 full-rate; R4 proved
// the 9-op min/max variant strictly worse)
__device__ __forceinline__ void ins5(float s[NKEEP], float nv) {
    float y0 = fmaxf(s[0], nv);
    float y1 = __builtin_amdgcn_fmed3f(s[0], s[1], nv);
    float y2 = __builtin_amdgcn_fmed3f(s[1], s[2], nv);
    float y3 = __builtin_amdgcn_fmed3f(s[2], s[3], nv);
    float y4 = __builtin_amdgcn_fmed3f(s[3], s[4], nv);
    s[0] = y0; s[1] = y1; s[2] = y2; s[3] = y3; s[4] = y4;
}

// ---------- kernel 0: bf16 convert + msq(-0.5*sq), 8 threads/row (R3 verbatim) ----------
__global__ __launch_bounds__(256) void prep_kernel(const float* __restrict__ x,
                                                   unsigned short* __restrict__ xb,
                                                   float* __restrict__ msq) {
    const int gid = blockIdx.x * 256 + threadIdx.x;   // 0..98303
    const int row = gid >> 3;
    const int h = gid & 7;
    float4 p = ((const float4*)(x + (size_t)row * D_F))[h];
    float s = p.x * p.x + p.y * p.y + p.z * p.z + p.w * p.w;
    s += __shfl_xor(s, 1, 64);
    s += __shfl_xor(s, 2, 64);
    s += __shfl_xor(s, 4, 64);
    const unsigned lo = (unsigned)f2bf(p.x) | ((unsigned)f2bf(p.y) << 16);
    const unsigned hi = (unsigned)f2bf(p.z) | ((unsigned)f2bf(p.w) << 16);
    ((uint2*)xb)[gid] = make_uint2(lo, hi);
    if (h == 0) msq[row] = -0.5f * s;
}

// ---------- kernel 1: MFMA gram + per-row top-5 (non-self) keys ----------
// R3's proven loop body, widened: each wave owns 64 query rows via 4 B-frags.
// The 4 MFMAs per subtile share ONE (a, m) pair — nothing for the register
// allocator to gain by serializing (R1's failure mode), and in program order
// MFMA k's 18-cyc result latency is covered by MFMAs k+1..3 issuing. Halves
// per-SIMD iteration count (144 vs 288) -> per-iteration fixed cost (waitcnt
// drain, result-latency nops, addressing) amortizes 2x. NO scheduling
// directives (R4/R5/R6 all proved them counterproductive here).
__global__ __launch_bounds__(BLOCK_T, 3) void topk_mfma(
    const unsigned short* __restrict__ xb, const float* __restrict__ msq,
    float* __restrict__ cand) {
    __shared__ alignas(16) char lds[LDS_BYTES];
    const int t = threadIdx.x;
    const int wave = t >> 6;
    const int lane = t & 63;
    const int quad = lane >> 4;
    const int l16 = lane & 15;

    const int rowbase = blockIdx.x * ROWS_PER_BLOCK + wave * 64;
    const int seg = blockIdx.y;
    const int j0 = seg * JSEG;

    // ---- stage segment A-tiles into LDS (each of 4 waves: 12 subtiles) ----
#pragma unroll
    for (int k = 0; k < SUBTILES / 4; ++k) {
        const int it = wave + 4 * k;
        const uint4 val = *((const uint4*)(xb + (size_t)(j0 + it * 16 + l16) * D_F) + quad);
        *((uint4*)(lds + it * 1024) + lane) = val;
    }
    if (wave == 0) {
#pragma unroll
        for (int k = 0; k < 3; ++k) {
            const uint4 val = *((const uint4*)(msq + j0) + k * 64 + lane);
            *((uint4*)(lds + M_OFF + k * 1024) + lane) = val;
        }
    }

    // B fragments: 4 x 16 query rows, register-resident
    bf16x8 bfrag[4];
#pragma unroll
    for (int rt = 0; rt < 4; ++rt)
        bfrag[rt] = *reinterpret_cast<const bf16x8*>(
            xb + (size_t)(rowbase + rt * 16 + l16) * D_F + quad * 8);

    __syncthreads();

    float tk[4][NKEEP];
#pragma unroll
    for (int rt = 0; rt < 4; ++rt)
#pragma unroll
        for (int k = 0; k < NKEEP; ++k) tk[rt][k] = NEGF;

    // lane's self position inside a matching subtile: quad*4+reg == l16
    const int selfreg = (quad == (l16 >> 2)) ? (l16 & 3) : 8;

    const char* aBase = lds + lane * 16;
    const char* mBase = lds + M_OFF + quad * 16;

#pragma unroll
    for (int it = 0; it < SUBTILES; ++it) {
        const bf16x8 a = *reinterpret_cast<const bf16x8*>(aBase + it * 1024);
        const f32x4 m = *reinterpret_cast<const f32x4*>(mBase + it * 64);

        f32x4 c0 = __builtin_amdgcn_mfma_f32_16x16x32_bf16(a, bfrag[0], m, 0, 0, 0);
        f32x4 c1 = __builtin_amdgcn_mfma_f32_16x16x32_bf16(a, bfrag[1], m, 0, 0, 0);
        f32x4 c2 = __builtin_amdgcn_mfma_f32_16x16x32_bf16(a, bfrag[2], m, 0, 0, 0);
        f32x4 c3 = __builtin_amdgcn_mfma_f32_16x16x32_bf16(a, bfrag[3], m, 0, 0, 0);

        const int jt = j0 + (it << 4);
        if (jt == rowbase) {          // wave-uniform: rt=0 self diag in this subtile
            c0[0] = (selfreg == 0) ? NEGF : c0[0];
            c0[1] = (selfreg == 1) ? NEGF : c0[1];
            c0[2] = (selfreg == 2) ? NEGF : c0[2];
            c0[3] = (selfreg == 3) ? NEGF : c0[3];
        }
        if (jt == rowbase + 16) {     // rt=1
            c1[0] = (selfreg == 0) ? NEGF : c1[0];
            c1[1] = (selfreg == 1) ? NEGF : c1[1];
            c1[2] = (selfreg == 2) ? NEGF : c1[2];
            c1[3] = (selfreg == 3) ? NEGF : c1[3];
        }
        if (jt == rowbase + 32) {     // rt=2
            c2[0] = (selfreg == 0) ? NEGF : c2[0];
            c2[1] = (selfreg == 1) ? NEGF : c2[1];
            c2[2] = (selfreg == 2) ? NEGF : c2[2];
            c2[3] = (selfreg == 3) ? NEGF : c2[3];
        }
        if (jt == rowbase + 48) {     // rt=3
            c3[0] = (selfreg == 0) ? NEGF : c3[0];
            c3[1] = (selfreg == 1) ? NEGF : c3[1];
            c3[2] = (selfreg == 2) ? NEGF : c3[2];
            c3[3] = (selfreg == 3) ? NEGF : c3[3];
        }

        ins5(tk[0], c0[0]); ins5(tk[0], c0[1]); ins5(tk[0], c0[2]); ins5(tk[0], c0[3]);
        ins5(tk[1], c1[0]); ins5(tk[1], c1[1]); ins5(tk[1], c1[2]); ins5(tk[1], c1[3]);
        ins5(tk[2], c2[0]); ins5(tk[2], c2[1]); ins5(tk[2], c2[2]); ins5(tk[2], c2[3]);
        ins5(tk[3], c3[0]); ins5(tk[3], c3[1]); ins5(tk[3], c3[2]); ins5(tk[3], c3[3]);
    }

    // ---- cross-quad merge via shuffles (row's lists live in 4 quads, same l16) ----
#pragma unroll
    for (int rt = 0; rt < 4; ++rt) {
#pragma unroll
        for (int rnd = 0; rnd < 2; ++rnd) {
            const int mask = 16 << rnd;
            float b[NKEEP];
#pragma unroll
            for (int k = 0; k < NKEEP; ++k) b[k] = __shfl_xor(tk[rt][k], mask, 64);
#pragma unroll
            for (int k = 0; k < NKEEP; ++k) ins5(tk[rt], b[k]);
        }
    }

    if (quad == 0) {
#pragma unroll
        for (int rt = 0; rt < 4; ++rt) {
            const int g = rowbase + rt * 16 + l16;
            float* dst = cand + ((size_t)g * SEGS + seg) * NKEEP;
#pragma unroll
            for (int k = 0; k < NKEEP; ++k) dst[k] = tk[rt][k];
        }
    }
}

// ---------- kernel 2: merge per-segment keys -> v, 4 threads/row (R3 verbatim) ----------
__global__ __launch_bounds__(256) void merge_v(const float* __restrict__ cand,
                                               const float* __restrict__ msq,
                                               float* __restrict__ v,
                                               float* __restrict__ out) {
    const int gid = blockIdx.x * 256 + threadIdx.x;   // 0..49151
    const int row = gid >> 2;
    const int h = gid & 3;
    const float4* c = (const float4*)(cand + (size_t)row * (SEGS * NKEEP));  // 20 x float4
    float mk[NKEEP];
#pragma unroll
    for (int k = 0; k < NKEEP; ++k) mk[k] = NEGF;
#pragma unroll
    for (int s = 0; s < 5; ++s) {
        float4 q = c[h + 4 * s];
        ins5(mk, q.x); ins5(mk, q.y); ins5(mk, q.z); ins5(mk, q.w);
    }
    // merge across the 4 lanes of this row (consecutive lanes, same wave)
#pragma unroll
    for (int rnd = 0; rnd < 2; ++rnd) {
        const int mask = 1 << rnd;
        float b[NKEEP];
#pragma unroll
        for (int k = 0; k < NKEEP; ++k) b[k] = __shfl_xor(mk[k], mask, 64);
#pragma unroll
        for (int k = 0; k < NKEEP; ++k) ins5(mk, b[k]);
    }
    if (h == 0) {
        const float msqi = msq[row];
        float ssum = 0.f;
#pragma unroll
        for (int m = 0; m < NKEEP; ++m) {
            const float d2 = -2.0f * (mk[m] + msqi);   // sq_i - 2*key
            ssum += expf(-sqrtf(fmaxf(d2, EPSF)));
        }
        const float vi = 1.0f - ssum / (float)KNN;
        v[row] = vi;
        out[2 * row] = vi;
        out[2 * row + 1] = 0.0f;
    }
}

// ---------- kernel 3: edge filtration (bf16 gather: 1 line per row, R3 verbatim) ----------
__global__ __launch_bounds__(256) void edge_kernel(const unsigned short* __restrict__ xb,
                                                   const int* __restrict__ ei,
                                                   const float* __restrict__ v,
                                                   float* __restrict__ out) {
    int e = blockIdx.x * 256 + threadIdx.x;
    if (e >= N_E) return;
    const int u = ei[e];
    const int w = ei[N_E + e];
    const uint4* xu = (const uint4*)(xb + (size_t)u * D_F);
    const uint4* xw = (const uint4*)(xb + (size_t)w * D_F);
    float acc = 0.f;
#pragma unroll
    for (int d = 0; d < 4; ++d) {
        const uint4 p = xu[d];
        const uint4 q = xw[d];
#pragma unroll
        for (int c = 0; c < 4; ++c) {
            const unsigned pu = (&p.x)[c];
            const unsigned qu = (&q.x)[c];
            const float d0 = bfu2f(pu) - bfu2f(qu);
            const float d1 = bfhi2f(pu) - bfhi2f(qu);
            acc = fmaf(d0, d0, acc);
            acc = fmaf(d1, d1, acc);
        }
    }
    const float enorm = sqrtf(fmaxf(acc, EPSF));
    const float ey = 1.0f - expf(-enorm);
    const float ev = fmaxf(v[u], v[w]);
    out[2 * (N_V + e) + 0] = ev;
    out[2 * (N_V + e) + 1] = ey;
}

extern "C" void kernel_launch(void* const* d_in, const int* in_sizes, int n_in,
                              void* d_out, int out_size, void* d_ws, size_t ws_size,
                              hipStream_t stream) {
    const float* x = (const float*)d_in[0];
    const int* ei = (const int*)d_in[1];
    float* out = (float*)d_out;
    char* ws = (char*)d_ws;

    unsigned short* xb = (unsigned short*)ws;                  // 786432 B
    float* msq = (float*)(ws + 786432);                        // 49152 B
    float* v   = (float*)(ws + 786432 + 49152);                // 49152 B
    float* cand = (float*)(ws + 786432 + 2 * 49152);           // 12288*16*5*4 = 3932160 B

    prep_kernel<<<(N_V * 8) / 256, 256, 0, stream>>>(x, xb, msq);

    dim3 g1(ROW_BLOCKS, SEGS);
    topk_mfma<<<g1, BLOCK_T, 0, stream>>>(xb, msq, cand);

    merge_v<<<(N_V * 4) / 256, 256, 0, stream>>>(cand, msq, v, out);

    edge_kernel<<<N_E / 256, 256, 0, stream>>>(xb, ei, v, out);
}